// Round 8
// baseline (107.692 us; speedup 1.0000x reference)
//
#include <hip/hip_runtime.h>
#include <hip/hip_fp16.h>

#define NN 3072
#define F 256
#define NH 8
#define ALPHA 0.2f
#define LN_EPS 1e-5f

typedef float f32x4 __attribute__((ext_vector_type(4)));
typedef _Float16 f16x8 __attribute__((ext_vector_type(8)));

// ---- Kernel A: h = x @ W^T; outputs hT fp16 [256][3072], a_src f32 [N][8],
// ---- a_dstT f32 [8][N] (transposed for contiguous k-reads in gat_mfma)
__global__ __launch_bounds__(256) void gemm_xwT(const float* __restrict__ x,
                                                const float* __restrict__ W,
                                                const float* __restrict__ asrc_w,
                                                const float* __restrict__ adst_w,
                                                _Float16* __restrict__ hT,
                                                float* __restrict__ a_src,
                                                float* __restrict__ a_dstT) {
  __shared__ float xs[8][F];
  const int t = threadIdx.x;
  const int bi = blockIdx.x;
  for (int r = 0; r < 8; ++r) xs[r][t] = x[(size_t)(bi * 8 + r) * F + t];
  __syncthreads();
  float acc[8];
#pragma unroll
  for (int r = 0; r < 8; ++r) acc[r] = 0.f;
  const float* wrow = W + (size_t)t * F;
  for (int k = 0; k < F; k += 4) {
    const float4 w4 = *(const float4*)(wrow + k);
#pragma unroll
    for (int r = 0; r < 8; ++r) {
      const float4 xv = *(const float4*)(&xs[r][k]);
      acc[r] += w4.x * xv.x + w4.y * xv.y + w4.z * xv.z + w4.w * xv.w;
    }
  }
  // hT[d=t][j=bi*8+r], 8 consecutive j -> one 16B store
  f16x8 hv;
#pragma unroll
  for (int r = 0; r < 8; ++r) hv[r] = (_Float16)acc[r];
  *(f16x8*)(hT + (size_t)t * NN + bi * 8) = hv;
  // per-head projections; col t weight = asrc_w[t]/adst_w[t]
  const float wsv = asrc_w[t];
  const float wdv = adst_w[t];
#pragma unroll
  for (int r = 0; r < 8; ++r) {
    float ps = acc[r] * wsv;
    float pd = acc[r] * wdv;
#pragma unroll
    for (int off = 1; off < 32; off <<= 1) {
      ps += __shfl_xor(ps, off);
      pd += __shfl_xor(pd, off);
    }
    if ((t & 31) == 0) {
      a_src[(size_t)(bi * 8 + r) * NH + (t >> 5)] = ps;
      a_dstT[(size_t)(t >> 5) * NN + bi * 8 + r] = pd;
    }
  }
}

// ---- Kernel C: dense-tile GAT aggregation via MFMA ----
// Block = (16-row i-tile, head-pair). 4 waves split K=3072 (768 each).
// A-frag (P, fp16) built in registers from logits; B-frag read from hT rows.
// No atomics: each block owns disjoint h_out[i-tile][64 cols].
__global__ __launch_bounds__(256) void gat_mfma(const float* __restrict__ adj,
                                                const _Float16* __restrict__ hT,
                                                const float* __restrict__ a_src,
                                                const float* __restrict__ a_dstT,
                                                const float* __restrict__ edge_W,
                                                const float* __restrict__ edge_b,
                                                float* __restrict__ h_out) {
  __shared__ float opart[4][16][68];  // stride-68 pad: aligned float4, 2-way banks
  __shared__ float swred[4][2][16];
  const int bid = blockIdx.x;
  const int it = bid % 192;           // i-tile (siblings 192 apart -> same XCD)
  const int hp = bid / 192;           // head-pair
  const int i0 = it * 16;
  const int h0 = hp * 2;
  const int t = threadIdx.x, w = t >> 6, lane = t & 63;
  const int col = lane & 15, kg = lane >> 4;

  const float ew0 = edge_W[h0], ew1 = edge_W[h0 + 1];
  const float base0 = a_src[(size_t)(i0 + col) * NH + h0] + edge_b[h0];
  const float base1 = a_src[(size_t)(i0 + col) * NH + h0 + 1] + edge_b[h0 + 1];

  f32x4 acc00 = {0.f, 0.f, 0.f, 0.f}, acc01 = acc00, acc10 = acc00, acc11 = acc00;
  float sw0 = 0.f, sw1 = 0.f;
  const float* arow = adj + (size_t)(i0 + col) * NN + w * 768 + kg * 8;
  const float* adp0 = a_dstT + (size_t)h0 * NN + w * 768 + kg * 8;
  const float* adp1 = adp0 + NN;
  const _Float16* hb0 = hT + (size_t)(h0 * 32 + col) * NN + w * 768 + kg * 8;
  const _Float16* hb1 = hb0 + (size_t)16 * NN;
  const _Float16* hb2 = hb0 + (size_t)32 * NN;
  const _Float16* hb3 = hb0 + (size_t)48 * NN;

  for (int ks = 0; ks < 24; ++ks) {
    const int j = ks * 32;
    const f32x4 av0 = *(const f32x4*)(arow + j);
    const f32x4 av1 = *(const f32x4*)(arow + j + 4);
    const f32x4 d00 = *(const f32x4*)(adp0 + j);
    const f32x4 d01 = *(const f32x4*)(adp0 + j + 4);
    const f32x4 d10 = *(const f32x4*)(adp1 + j);
    const f32x4 d11 = *(const f32x4*)(adp1 + j + 4);
    const f16x8 b00 = *(const f16x8*)(hb0 + j);
    const f16x8 b01 = *(const f16x8*)(hb1 + j);
    const f16x8 b10 = *(const f16x8*)(hb2 + j);
    const f16x8 b11 = *(const f16x8*)(hb3 + j);
    const float avv[8] = {av0.x, av0.y, av0.z, av0.w, av1.x, av1.y, av1.z, av1.w};
    const float dd0[8] = {d00.x, d00.y, d00.z, d00.w, d01.x, d01.y, d01.z, d01.w};
    const float dd1[8] = {d10.x, d10.y, d10.z, d10.w, d11.x, d11.y, d11.z, d11.w};
    f16x8 a0, a1;
#pragma unroll
    for (int e = 0; e < 8; ++e) {
      const float av = avv[e];
      float l0 = fmaf(av, ew0, base0 + dd0[e]);
      l0 = fmaxf(l0, ALPHA * l0);
      const float w0 = (av > 0.f) ? __expf(l0) : 0.f;
      a0[e] = (_Float16)w0;
      sw0 += w0;
      float l1 = fmaf(av, ew1, base1 + dd1[e]);
      l1 = fmaxf(l1, ALPHA * l1);
      const float w1 = (av > 0.f) ? __expf(l1) : 0.f;
      a1[e] = (_Float16)w1;
      sw1 += w1;
    }
    acc00 = __builtin_amdgcn_mfma_f32_16x16x32_f16(a0, b00, acc00, 0, 0, 0);
    acc01 = __builtin_amdgcn_mfma_f32_16x16x32_f16(a0, b01, acc01, 0, 0, 0);
    acc10 = __builtin_amdgcn_mfma_f32_16x16x32_f16(a1, b10, acc10, 0, 0, 0);
    acc11 = __builtin_amdgcn_mfma_f32_16x16x32_f16(a1, b11, acc11, 0, 0, 0);
  }
  // denominator: lanes {col, col+16, col+32, col+48} hold partials for row=col
  sw0 += __shfl_xor(sw0, 16);
  sw0 += __shfl_xor(sw0, 32);
  sw1 += __shfl_xor(sw1, 16);
  sw1 += __shfl_xor(sw1, 32);
  if (lane < 16) {
    swred[w][0][lane] = sw0;
    swred[w][1][lane] = sw1;
  }
  // C/D layout (16x16): col=lane&15, row=(lane>>4)*4+reg
#pragma unroll
  for (int r = 0; r < 4; ++r) {
    opart[w][kg * 4 + r][col] = acc00[r];
    opart[w][kg * 4 + r][16 + col] = acc01[r];
    opart[w][kg * 4 + r][32 + col] = acc10[r];
    opart[w][kg * 4 + r][48 + col] = acc11[r];
  }
  __syncthreads();
  // final: thread t -> (row r, 4 cols c4), sum 4 waves, normalize, store
  const int r = t >> 4, c4 = (t & 15) * 4;
  f32x4 o = *(const f32x4*)&opart[0][r][c4];
  o += *(const f32x4*)&opart[1][r][c4];
  o += *(const f32x4*)&opart[2][r][c4];
  o += *(const f32x4*)&opart[3][r][c4];
  const int hh = (t & 15) >> 3;
  const float s = swred[0][hh][r] + swred[1][hh][r] + swred[2][hh][r] + swred[3][hh][r];
  o /= s;
  *(f32x4*)(h_out + (size_t)(i0 + r) * F + hp * 64 + c4) = o;
}

// ---- Kernel D: y = h_out @ fuse_W^T + b, LayerNorm, ReLU ----
__global__ __launch_bounds__(256) void fuse_ln(const float* __restrict__ hin,
                                               const float* __restrict__ fW,
                                               const float* __restrict__ fb,
                                               const float* __restrict__ ln_g,
                                               const float* __restrict__ ln_b,
                                               float* __restrict__ out) {
  __shared__ float xs[8][F];
  __shared__ float ys[8][F];
  __shared__ float mu_s[8], rs_s[8];
  const int t = threadIdx.x;
  const int bi = blockIdx.x;
  for (int r = 0; r < 8; ++r) xs[r][t] = hin[(size_t)(bi * 8 + r) * F + t];
  __syncthreads();
  float acc[8];
#pragma unroll
  for (int r = 0; r < 8; ++r) acc[r] = 0.f;
  const float* wrow = fW + (size_t)t * F;
  for (int k = 0; k < F; k += 4) {
    const float4 w4 = *(const float4*)(wrow + k);
#pragma unroll
    for (int r = 0; r < 8; ++r) {
      const float4 xv = *(const float4*)(&xs[r][k]);
      acc[r] += w4.x * xv.x + w4.y * xv.y + w4.z * xv.z + w4.w * xv.w;
    }
  }
  const float fbt = fb[t];
  for (int r = 0; r < 8; ++r) ys[r][t] = acc[r] + fbt;
  __syncthreads();
  {
    const int r = t >> 5, c0 = t & 31;
    float sm = 0.f, sq = 0.f;
    for (int cc = c0; cc < F; cc += 32) {
      const float vv = ys[r][cc];
      sm += vv;
      sq += vv * vv;
    }
#pragma unroll
    for (int off = 1; off < 32; off <<= 1) {
      sm += __shfl_xor(sm, off);
      sq += __shfl_xor(sq, off);
    }
    if (c0 == 0) {
      const float mu = sm * (1.f / F);
      const float var = sq * (1.f / F) - mu * mu;
      mu_s[r] = mu;
      rs_s[r] = rsqrtf(var + LN_EPS);
    }
  }
  __syncthreads();
  const float g = ln_g[t], b = ln_b[t];
  for (int r = 0; r < 8; ++r) {
    const float vv = (ys[r][t] - mu_s[r]) * rs_s[r] * g + b;
    out[(size_t)(bi * 8 + r) * F + t] = fmaxf(vv, 0.f);
  }
}

extern "C" void kernel_launch(void* const* d_in, const int* in_sizes, int n_in,
                              void* d_out, int out_size, void* d_ws, size_t ws_size,
                              hipStream_t stream) {
  const float* x = (const float*)d_in[0];
  const float* adj = (const float*)d_in[1];
  const float* W = (const float*)d_in[2];
  const float* attn_src = (const float*)d_in[3];
  const float* attn_dst = (const float*)d_in[4];
  const float* edge_W = (const float*)d_in[5];
  const float* edge_b = (const float*)d_in[6];
  const float* fuse_W = (const float*)d_in[7];
  const float* fuse_b = (const float*)d_in[8];
  const float* ln_g = (const float*)d_in[9];
  const float* ln_b = (const float*)d_in[10];
  float* out = (float*)d_out;

  float* ws = (float*)d_ws;
  _Float16* hT = (_Float16*)ws;                     // 256*3072 halves = 393216 floats
  float* a_src = ws + (size_t)256 * NN / 2;         // N*8
  float* a_dstT = a_src + (size_t)NN * NH;          // 8*N
  float* h_out = a_dstT + (size_t)NN * NH;          // N*F f32

  gemm_xwT<<<NN / 8, 256, 0, stream>>>(x, W, attn_src, attn_dst, hT, a_src, a_dstT);
  gat_mfma<<<192 * 4, 256, 0, stream>>>(adj, hT, a_src, a_dstT, edge_W, edge_b, h_out);
  fuse_ln<<<NN / 8, 256, 0, stream>>>(h_out, fuse_W, fuse_b, ln_g, ln_b, out);
}

// Round 9
// 103.350 us; speedup vs baseline: 1.0420x; 1.0420x over previous
//
#include <hip/hip_runtime.h>
#include <hip/hip_fp16.h>

#define NN 3072
#define F 256
#define NH 8
#define ALPHA 0.2f
#define LN_EPS 1e-5f
#define KC 4          // K-chunks
#define KCL (NN / KC) // 768 per chunk

typedef float f32x4 __attribute__((ext_vector_type(4)));
typedef _Float16 f16x8 __attribute__((ext_vector_type(8)));

// ---- Kernel A: h = x @ W^T; outputs hblk f16 [j/32][d=256][j%32] (B-frag
// ---- friendly blocked layout), a_src f32 [N][8], a_dstT f32 [8][N].
__global__ __launch_bounds__(256) void gemm_xwT(const float* __restrict__ x,
                                                const float* __restrict__ W,
                                                const float* __restrict__ asrc_w,
                                                const float* __restrict__ adst_w,
                                                _Float16* __restrict__ hblk,
                                                float* __restrict__ a_src,
                                                float* __restrict__ a_dstT) {
  __shared__ float xs[8][F];
  const int t = threadIdx.x;
  const int bi = blockIdx.x;
  for (int r = 0; r < 8; ++r) xs[r][t] = x[(size_t)(bi * 8 + r) * F + t];
  __syncthreads();
  float acc[8];
#pragma unroll
  for (int r = 0; r < 8; ++r) acc[r] = 0.f;
  const float* wrow = W + (size_t)t * F;
  for (int k = 0; k < F; k += 4) {
    const float4 w4 = *(const float4*)(wrow + k);
#pragma unroll
    for (int r = 0; r < 8; ++r) {
      const float4 xv = *(const float4*)(&xs[r][k]);
      acc[r] += w4.x * xv.x + w4.y * xv.y + w4.z * xv.z + w4.w * xv.w;
    }
  }
  // blocked store: j = bi*8+r -> jb = bi>>2, jj = (bi&3)*8 + r
  f16x8 hv;
#pragma unroll
  for (int r = 0; r < 8; ++r) hv[r] = (_Float16)acc[r];
  *(f16x8*)(hblk + (size_t)(bi >> 2) * (F * 32) + t * 32 + (bi & 3) * 8) = hv;
  // per-head projections; col t weight = asrc_w[t]/adst_w[t]
  const float wsv = asrc_w[t];
  const float wdv = adst_w[t];
#pragma unroll
  for (int r = 0; r < 8; ++r) {
    float ps = acc[r] * wsv;
    float pd = acc[r] * wdv;
#pragma unroll
    for (int off = 1; off < 32; off <<= 1) {
      ps += __shfl_xor(ps, off);
      pd += __shfl_xor(pd, off);
    }
    if ((t & 31) == 0) {
      a_src[(size_t)(bi * 8 + r) * NH + (t >> 5)] = ps;
      a_dstT[(size_t)(t >> 5) * NN + bi * 8 + r] = pd;
    }
  }
}

// ---- Kernel C: dense-tile GAT aggregation via MFMA, v2 ----
// Block = (16-row i-tile, K-chunk). 4 waves = 4 head-pairs / d-quadrants.
// A-frag (P, f16) built in registers from logits; B-frag = contiguous 1KB
// windows of hblk. No block barriers; partial sums to ws (f16) + sw (f32).
__global__ __launch_bounds__(256) void gat_mfma(const float* __restrict__ adj,
                                                const _Float16* __restrict__ hblk,
                                                const float* __restrict__ a_src,
                                                const float* __restrict__ a_dstT,
                                                const float* __restrict__ edge_W,
                                                const float* __restrict__ edge_b,
                                                _Float16* __restrict__ part,
                                                float* __restrict__ swp) {
  __shared__ float opart[4][16][68];
  const int bid = blockIdx.x;
  const int i0 = (bid % 192) * 16;
  const int kc = bid / 192;
  const int t = threadIdx.x, w = t >> 6, lane = t & 63;
  const int col = lane & 15, kg = lane >> 4;
  const int h0 = w * 2, h1 = h0 + 1, d0 = w * 64;
  const float ew0 = edge_W[h0], ew1 = edge_W[h1];
  const float base0 = a_src[(size_t)(i0 + col) * NH + h0] + edge_b[h0];
  const float base1 = a_src[(size_t)(i0 + col) * NH + h1] + edge_b[h1];
  const float* arow = adj + (size_t)(i0 + col) * NN;
  const float* dT0 = a_dstT + (size_t)h0 * NN;
  const float* dT1 = a_dstT + (size_t)h1 * NN;

  f32x4 acc00 = {0.f, 0.f, 0.f, 0.f}, acc01 = acc00, acc10 = acc00, acc11 = acc00;
  float sw0 = 0.f, sw1 = 0.f;
  const int jc0 = kc * KCL;
  for (int sj = 0; sj < KCL; sj += 32) {
    const int jb = jc0 + sj;       // 32-aligned window base
    const int jl = jb + kg * 8;    // this lane's 8-j slice
    const f32x4 av0 = __builtin_nontemporal_load((const f32x4*)(arow + jl));
    const f32x4 av1 = __builtin_nontemporal_load((const f32x4*)(arow + jl + 4));
    const f32x4 d00 = *(const f32x4*)(dT0 + jl);
    const f32x4 d01 = *(const f32x4*)(dT0 + jl + 4);
    const f32x4 d10 = *(const f32x4*)(dT1 + jl);
    const f32x4 d11 = *(const f32x4*)(dT1 + jl + 4);
    const _Float16* bp = hblk + (size_t)(jb >> 5) * (F * 32) + kg * 8;
    const f16x8 b00 = *(const f16x8*)(bp + (d0 + col) * 32);
    const f16x8 b01 = *(const f16x8*)(bp + (d0 + 16 + col) * 32);
    const f16x8 b10 = *(const f16x8*)(bp + (d0 + 32 + col) * 32);
    const f16x8 b11 = *(const f16x8*)(bp + (d0 + 48 + col) * 32);
    f16x8 a0, a1;
#pragma unroll
    for (int e = 0; e < 8; ++e) {
      const float av = (e < 4) ? av0[e] : av1[e - 4];
      const float dv0 = (e < 4) ? d00[e] : d01[e - 4];
      const float dv1 = (e < 4) ? d10[e] : d11[e - 4];
      float l0 = fmaf(av, ew0, base0 + dv0);
      l0 = fmaxf(l0, ALPHA * l0);
      const float w0 = (av > 0.f) ? __expf(l0) : 0.f;
      sw0 += w0;
      a0[e] = (_Float16)w0;
      float l1 = fmaf(av, ew1, base1 + dv1);
      l1 = fmaxf(l1, ALPHA * l1);
      const float w1 = (av > 0.f) ? __expf(l1) : 0.f;
      sw1 += w1;
      a1[e] = (_Float16)w1;
    }
    acc00 = __builtin_amdgcn_mfma_f32_16x16x32_f16(a0, b00, acc00, 0, 0, 0);
    acc01 = __builtin_amdgcn_mfma_f32_16x16x32_f16(a0, b01, acc01, 0, 0, 0);
    acc10 = __builtin_amdgcn_mfma_f32_16x16x32_f16(a1, b10, acc10, 0, 0, 0);
    acc11 = __builtin_amdgcn_mfma_f32_16x16x32_f16(a1, b11, acc11, 0, 0, 0);
  }
  // denominators: sum over kg groups (lanes {l, l^16, l^32, l^48} share row=col)
  sw0 += __shfl_xor(sw0, 16);
  sw0 += __shfl_xor(sw0, 32);
  sw1 += __shfl_xor(sw1, 16);
  sw1 += __shfl_xor(sw1, 32);
  if (lane < 16) {
    swp[((size_t)kc * NN + i0 + col) * NH + h0] = sw0;
    swp[((size_t)kc * NN + i0 + col) * NH + h1] = sw1;
  }
  // stage accs (C layout: col=lane&15, row=kg*4+reg), then coalesced f16 stores
#pragma unroll
  for (int r = 0; r < 4; ++r) {
    opart[w][kg * 4 + r][col] = acc00[r];
    opart[w][kg * 4 + r][16 + col] = acc01[r];
    opart[w][kg * 4 + r][32 + col] = acc10[r];
    opart[w][kg * 4 + r][48 + col] = acc11[r];
  }
  // wave-private LDS round-trip (no barrier needed)
  const int rr = col, cg = kg;  // row rr, 16-col group cg
  f16x8 o0, o1;
#pragma unroll
  for (int q = 0; q < 8; ++q) {
    o0[q] = (_Float16)opart[w][rr][cg * 16 + q];
    o1[q] = (_Float16)opart[w][rr][cg * 16 + 8 + q];
  }
  _Float16* pdst = part + ((size_t)kc * NN + i0 + rr) * F + d0 + cg * 16;
  *(f16x8*)(pdst) = o0;
  *(f16x8*)(pdst + 8) = o1;
}

// ---- Kernel D: reduce K-chunk partials, normalize, GEMM fuse_W^T, LN, ReLU ----
__global__ __launch_bounds__(256) void fuse_ln(const _Float16* __restrict__ part,
                                               const float* __restrict__ swp,
                                               const float* __restrict__ fW,
                                               const float* __restrict__ fb,
                                               const float* __restrict__ ln_g,
                                               const float* __restrict__ ln_b,
                                               float* __restrict__ out) {
  __shared__ float xs[8][F];
  __shared__ float ys[8][F];
  __shared__ float mu_s[8], rs_s[8];
  const int t = threadIdx.x;
  const int bi = blockIdx.x;
  {
    const int rr = t >> 5, c8 = (t & 31) * 8;
    const int row_g = bi * 8 + rr;
    const int hh = (t & 31) >> 2;  // c8>>5
    float sm8[8];
#pragma unroll
    for (int q = 0; q < 8; ++q) sm8[q] = 0.f;
    float s = 0.f;
#pragma unroll
    for (int p = 0; p < KC; ++p) {
      const f16x8 pv = *(const f16x8*)(part + ((size_t)p * NN + row_g) * F + c8);
#pragma unroll
      for (int q = 0; q < 8; ++q) sm8[q] += (float)pv[q];
      s += swp[((size_t)p * NN + row_g) * NH + hh];
    }
    const float inv = 1.f / s;
#pragma unroll
    for (int q = 0; q < 8; ++q) xs[rr][c8 + q] = sm8[q] * inv;
  }
  __syncthreads();
  float acc[8];
#pragma unroll
  for (int r = 0; r < 8; ++r) acc[r] = 0.f;
  const float* wrow = fW + (size_t)t * F;
  for (int k = 0; k < F; k += 4) {
    const float4 w4 = *(const float4*)(wrow + k);
#pragma unroll
    for (int r = 0; r < 8; ++r) {
      const float4 xv = *(const float4*)(&xs[r][k]);
      acc[r] += w4.x * xv.x + w4.y * xv.y + w4.z * xv.z + w4.w * xv.w;
    }
  }
  const float fbt = fb[t];
  for (int r = 0; r < 8; ++r) ys[r][t] = acc[r] + fbt;
  __syncthreads();
  {
    const int r = t >> 5, c0 = t & 31;
    float sm = 0.f, sq = 0.f;
    for (int cc = c0; cc < F; cc += 32) {
      const float vv = ys[r][cc];
      sm += vv;
      sq += vv * vv;
    }
#pragma unroll
    for (int off = 1; off < 32; off <<= 1) {
      sm += __shfl_xor(sm, off);
      sq += __shfl_xor(sq, off);
    }
    if (c0 == 0) {
      const float mu = sm * (1.f / F);
      const float var = sq * (1.f / F) - mu * mu;
      mu_s[r] = mu;
      rs_s[r] = rsqrtf(var + LN_EPS);
    }
  }
  __syncthreads();
  const float g = ln_g[t], b = ln_b[t];
  for (int r = 0; r < 8; ++r) {
    const float vv = (ys[r][t] - mu_s[r]) * rs_s[r] * g + b;
    out[(size_t)(bi * 8 + r) * F + t] = fmaxf(vv, 0.f);
  }
}

extern "C" void kernel_launch(void* const* d_in, const int* in_sizes, int n_in,
                              void* d_out, int out_size, void* d_ws, size_t ws_size,
                              hipStream_t stream) {
  const float* x = (const float*)d_in[0];
  const float* adj = (const float*)d_in[1];
  const float* W = (const float*)d_in[2];
  const float* attn_src = (const float*)d_in[3];
  const float* attn_dst = (const float*)d_in[4];
  const float* edge_W = (const float*)d_in[5];
  const float* edge_b = (const float*)d_in[6];
  const float* fuse_W = (const float*)d_in[7];
  const float* fuse_b = (const float*)d_in[8];
  const float* ln_g = (const float*)d_in[9];
  const float* ln_b = (const float*)d_in[10];
  float* out = (float*)d_out;

  float* ws = (float*)d_ws;
  _Float16* hblk = (_Float16*)ws;                    // 96*256*32 f16 = 393216 floats
  float* a_src = ws + 393216;                        // N*8
  float* a_dstT = a_src + (size_t)NN * NH;           // 8*N
  float* swp = a_dstT + (size_t)NN * NH;             // KC*N*8
  _Float16* part = (_Float16*)(swp + (size_t)KC * NN * NH);  // KC*N*F f16

  gemm_xwT<<<NN / 8, 256, 0, stream>>>(x, W, attn_src, attn_dst, hblk, a_src, a_dstT);
  gat_mfma<<<192 * KC, 256, 0, stream>>>(adj, hblk, a_src, a_dstT, edge_W, edge_b, part, swp);
  fuse_ln<<<NN / 8, 256, 0, stream>>>(part, swp, fuse_W, fuse_b, ln_g, ln_b, out);
}

// Round 10
// 82.400 us; speedup vs baseline: 1.3069x; 1.2542x over previous
//
#include <hip/hip_runtime.h>
#include <hip/hip_fp16.h>

#define NN 3072
#define F 256
#define NH 8
#define ALPHA 0.2f
#define LN_EPS 1e-5f

typedef float f32x4 __attribute__((ext_vector_type(4)));
typedef _Float16 f16x8 __attribute__((ext_vector_type(8)));

// ============ Kernel A: h = x @ W^T via MFMA (f16 in, f32 acc) ============
// 16 rows/block (grid 192), 4 waves x 4 col-groups of 16.
// Outputs: hblk f16 [j/32][d=256][j%32], a_src f32 [N][8], a_dstT f32 [8][N].
__global__ __launch_bounds__(256) void gemm_h_mfma(const float* __restrict__ x,
                                                   const float* __restrict__ W,
                                                   const float* __restrict__ asrc_w,
                                                   const float* __restrict__ adst_w,
                                                   _Float16* __restrict__ hblk,
                                                   float* __restrict__ a_src,
                                                   float* __restrict__ a_dstT) {
  __shared__ _Float16 ys[16][264];
  const int t = threadIdx.x, w = t >> 6, l = t & 63;
  const int col = l & 15, kg = l >> 4;
  const int i0 = blockIdx.x * 16;
  const int cbase = w * 64 + col;
  f32x4 acc0 = {0.f, 0.f, 0.f, 0.f}, acc1 = acc0, acc2 = acc0, acc3 = acc0;
  const float* xrow = x + (size_t)(i0 + col) * F + kg * 8;
  const float* wr0 = W + (size_t)cbase * F + kg * 8;
  const float* wr1 = wr0 + (size_t)16 * F;
  const float* wr2 = wr0 + (size_t)32 * F;
  const float* wr3 = wr0 + (size_t)48 * F;
  for (int ks = 0; ks < 8; ++ks) {
    const int k0 = ks * 32;
    f16x8 af, bf0, bf1, bf2, bf3;
    {
      const f32x4 a = *(const f32x4*)(xrow + k0);
      const f32x4 b = *(const f32x4*)(xrow + k0 + 4);
#pragma unroll
      for (int e = 0; e < 4; ++e) { af[e] = (_Float16)a[e]; af[4 + e] = (_Float16)b[e]; }
    }
#define LDB(dst, ptr)                                                     \
    {                                                                     \
      const f32x4 a = *(const f32x4*)((ptr) + k0);                        \
      const f32x4 b = *(const f32x4*)((ptr) + k0 + 4);                    \
      _Pragma("unroll")                                                   \
      for (int e = 0; e < 4; ++e) { dst[e] = (_Float16)a[e]; dst[4 + e] = (_Float16)b[e]; } \
    }
    LDB(bf0, wr0) LDB(bf1, wr1) LDB(bf2, wr2) LDB(bf3, wr3)
#undef LDB
    acc0 = __builtin_amdgcn_mfma_f32_16x16x32_f16(af, bf0, acc0, 0, 0, 0);
    acc1 = __builtin_amdgcn_mfma_f32_16x16x32_f16(af, bf1, acc1, 0, 0, 0);
    acc2 = __builtin_amdgcn_mfma_f32_16x16x32_f16(af, bf2, acc2, 0, 0, 0);
    acc3 = __builtin_amdgcn_mfma_f32_16x16x32_f16(af, bf3, acc3, 0, 0, 0);
  }
  // ---- a_src / a_dstT epilogue (heads 2w, 2w+1 live in this wave's 64 cols)
  const float ws0 = asrc_w[cbase], ws1 = asrc_w[cbase + 16],
              ws2 = asrc_w[cbase + 32], ws3 = asrc_w[cbase + 48];
  const float wd0 = adst_w[cbase], wd1 = adst_w[cbase + 16],
              wd2 = adst_w[cbase + 32], wd3 = adst_w[cbase + 48];
#pragma unroll
  for (int r = 0; r < 4; ++r) {
    float p0 = acc0[r] * ws0 + acc1[r] * ws1;
    float p1 = acc2[r] * ws2 + acc3[r] * ws3;
    float q0 = acc0[r] * wd0 + acc1[r] * wd1;
    float q1 = acc2[r] * wd2 + acc3[r] * wd3;
#pragma unroll
    for (int off = 1; off < 16; off <<= 1) {
      p0 += __shfl_xor(p0, off); p1 += __shfl_xor(p1, off);
      q0 += __shfl_xor(q0, off); q1 += __shfl_xor(q1, off);
    }
    if (col == 0) {
      const int row = i0 + kg * 4 + r;
      const int h0 = w * 2;
      a_src[(size_t)row * NH + h0] = p0;
      a_src[(size_t)row * NH + h0 + 1] = p1;
      a_dstT[(size_t)h0 * NN + row] = q0;
      a_dstT[(size_t)(h0 + 1) * NN + row] = q1;
    }
  }
  // ---- hblk store via LDS transpose (C layout: row=kg*4+r, col=cg*16+col)
#pragma unroll
  for (int r = 0; r < 4; ++r) {
    ys[kg * 4 + r][w * 64 + col] = (_Float16)acc0[r];
    ys[kg * 4 + r][w * 64 + 16 + col] = (_Float16)acc1[r];
    ys[kg * 4 + r][w * 64 + 32 + col] = (_Float16)acc2[r];
    ys[kg * 4 + r][w * 64 + 48 + col] = (_Float16)acc3[r];
  }
  __syncthreads();
  const int jb = i0 >> 5, jjb = i0 & 31;
  f16x8 hv0, hv1;
#pragma unroll
  for (int q = 0; q < 8; ++q) { hv0[q] = ys[q][t]; hv1[q] = ys[8 + q][t]; }
  *(f16x8*)(hblk + (size_t)jb * (F * 32) + t * 32 + jjb) = hv0;
  *(f16x8*)(hblk + (size_t)jb * (F * 32) + t * 32 + jjb + 8) = hv1;
}

// ============ Kernel C: dense-tile GAT aggregation via MFMA, v3 ============
// Block = (16-row i-tile, K-chunk of NN/KCn). 4 waves = 4 head-pairs/d-quads.
// Adjacency/a_dst loads double-buffered (HBM latency); hblk single (L2).
struct KBuf { f32x4 av0, av1, d00, d01, d10, d11; };

template <int KCn>
__global__ __launch_bounds__(256, 4) void gat_mfma(const float* __restrict__ adj,
                                                   const _Float16* __restrict__ hblk,
                                                   const float* __restrict__ a_src,
                                                   const float* __restrict__ a_dstT,
                                                   const float* __restrict__ edge_W,
                                                   const float* __restrict__ edge_b,
                                                   _Float16* __restrict__ part,
                                                   float* __restrict__ swp) {
  __shared__ float opart[4][16][68];
  const int bid = blockIdx.x;
  const int i0 = (bid % 192) * 16;
  const int kc = bid / 192;
  const int t = threadIdx.x, w = t >> 6, lane = t & 63;
  const int col = lane & 15, kg = lane >> 4;
  const int h0 = w * 2, h1 = h0 + 1, d0 = w * 64;
  const float ew0 = edge_W[h0], ew1 = edge_W[h1];
  const float base0 = a_src[(size_t)(i0 + col) * NH + h0] + edge_b[h0];
  const float base1 = a_src[(size_t)(i0 + col) * NH + h1] + edge_b[h1];
  const float* arow = adj + (size_t)(i0 + col) * NN;
  const float* dT0 = a_dstT + (size_t)h0 * NN;
  const float* dT1 = a_dstT + (size_t)h1 * NN;
  const int kg8 = kg * 8;

  f32x4 acc00 = {0.f, 0.f, 0.f, 0.f}, acc01 = acc00, acc10 = acc00, acc11 = acc00;
  float sw0 = 0.f, sw1 = 0.f;
  constexpr int KCL = NN / KCn;
  constexpr int NSTEP = KCL / 32;  // 12 (KC=8) or 24 (KC=4), both even
  const int jc0 = kc * KCL;

#define GLOAD(B, base_)                                                        \
  {                                                                            \
    const int jl_ = (base_) + kg8;                                             \
    B.av0 = __builtin_nontemporal_load((const f32x4*)(arow + jl_));            \
    B.av1 = __builtin_nontemporal_load((const f32x4*)(arow + jl_ + 4));        \
    B.d00 = *(const f32x4*)(dT0 + jl_);                                        \
    B.d01 = *(const f32x4*)(dT0 + jl_ + 4);                                    \
    B.d10 = *(const f32x4*)(dT1 + jl_);                                        \
    B.d11 = *(const f32x4*)(dT1 + jl_ + 4);                                    \
  }

#define KCOMP(B, jbv)                                                          \
  {                                                                            \
    const _Float16* bp = hblk + (size_t)((jbv) >> 5) * (F * 32) + kg8;         \
    const f16x8 b00 = *(const f16x8*)(bp + (d0 + col) * 32);                   \
    const f16x8 b01 = *(const f16x8*)(bp + (d0 + 16 + col) * 32);              \
    const f16x8 b10 = *(const f16x8*)(bp + (d0 + 32 + col) * 32);              \
    const f16x8 b11 = *(const f16x8*)(bp + (d0 + 48 + col) * 32);              \
    f16x8 a0, a1;                                                              \
    _Pragma("unroll")                                                          \
    for (int e = 0; e < 8; ++e) {                                              \
      const float av = (e < 4) ? B.av0[e & 3] : B.av1[e & 3];                  \
      const float dv0 = (e < 4) ? B.d00[e & 3] : B.d01[e & 3];                 \
      const float dv1 = (e < 4) ? B.d10[e & 3] : B.d11[e & 3];                 \
      float l0 = fmaf(av, ew0, base0 + dv0);                                   \
      l0 = fmaxf(l0, ALPHA * l0);                                              \
      const float w0_ = (av > 0.f) ? __expf(l0) : 0.f;                         \
      sw0 += w0_; a0[e] = (_Float16)w0_;                                       \
      float l1 = fmaf(av, ew1, base1 + dv1);                                   \
      l1 = fmaxf(l1, ALPHA * l1);                                              \
      const float w1_ = (av > 0.f) ? __expf(l1) : 0.f;                         \
      sw1 += w1_; a1[e] = (_Float16)w1_;                                       \
    }                                                                          \
    acc00 = __builtin_amdgcn_mfma_f32_16x16x32_f16(a0, b00, acc00, 0, 0, 0);   \
    acc01 = __builtin_amdgcn_mfma_f32_16x16x32_f16(a0, b01, acc01, 0, 0, 0);   \
    acc10 = __builtin_amdgcn_mfma_f32_16x16x32_f16(a1, b10, acc10, 0, 0, 0);   \
    acc11 = __builtin_amdgcn_mfma_f32_16x16x32_f16(a1, b11, acc11, 0, 0, 0);   \
  }

  KBuf A, B;
  int jb = jc0;
  GLOAD(A, jb);
  for (int s = 0; s < NSTEP; s += 2) {
    GLOAD(B, jb + 32);
    KCOMP(A, jb);
    if (s + 2 < NSTEP) GLOAD(A, jb + 64);
    KCOMP(B, jb + 32);
    jb += 64;
  }
#undef GLOAD
#undef KCOMP

  // denominators: reduce over kg groups
  sw0 += __shfl_xor(sw0, 16); sw0 += __shfl_xor(sw0, 32);
  sw1 += __shfl_xor(sw1, 16); sw1 += __shfl_xor(sw1, 32);
  if (lane < 16) {
    swp[((size_t)kc * NN + i0 + col) * NH + h0] = sw0;
    swp[((size_t)kc * NN + i0 + col) * NH + h1] = sw1;
  }
  // stage accs, wave-private transpose, packed f16 stores
#pragma unroll
  for (int r = 0; r < 4; ++r) {
    opart[w][kg * 4 + r][col] = acc00[r];
    opart[w][kg * 4 + r][16 + col] = acc01[r];
    opart[w][kg * 4 + r][32 + col] = acc10[r];
    opart[w][kg * 4 + r][48 + col] = acc11[r];
  }
  const int rr = col, cg = kg;
  f16x8 o0, o1;
#pragma unroll
  for (int q = 0; q < 8; ++q) {
    o0[q] = (_Float16)opart[w][rr][cg * 16 + q];
    o1[q] = (_Float16)opart[w][rr][cg * 16 + 8 + q];
  }
  _Float16* pdst = part + ((size_t)kc * NN + i0 + rr) * F + d0 + cg * 16;
  *(f16x8*)(pdst) = o0;
  *(f16x8*)(pdst + 8) = o1;
}

// ============ Kernel D: reduce partials + normalize + MFMA GEMM + LN + ReLU ====
template <int KCn>
__global__ __launch_bounds__(256) void fuse_ln_mfma(const _Float16* __restrict__ part,
                                                    const float* __restrict__ swp,
                                                    const float* __restrict__ fW,
                                                    const float* __restrict__ fb,
                                                    const float* __restrict__ ln_g,
                                                    const float* __restrict__ ln_b,
                                                    float* __restrict__ out) {
  __shared__ _Float16 xs[16][264];
  __shared__ float ssum[16][NH];
  __shared__ float red[2][4][16];
  const int t = threadIdx.x, w = t >> 6, l = t & 63;
  const int col = l & 15, kg = l >> 4;
  const int i0 = blockIdx.x * 16;
  // per-(row,head) denominators
  if (t < 128) {
    const int r = t >> 3, hh = t & 7;
    float s = 0.f;
#pragma unroll
    for (int p = 0; p < KCn; ++p) s += swp[((size_t)p * NN + i0 + r) * NH + hh];
    ssum[r][hh] = s;
  }
  __syncthreads();
  // reduce partials, normalize, stage f16 A-tile
  {
    const int c8 = (t & 31) * 8;
    const int hh = (t & 31) >> 2;
#pragma unroll
    for (int rp = 0; rp < 2; ++rp) {
      const int rr = (t >> 5) + rp * 8;
      float sm8[8];
#pragma unroll
      for (int q = 0; q < 8; ++q) sm8[q] = 0.f;
#pragma unroll
      for (int p = 0; p < KCn; ++p) {
        const f16x8 v = *(const f16x8*)(part + ((size_t)p * NN + i0 + rr) * F + c8);
#pragma unroll
        for (int q = 0; q < 8; ++q) sm8[q] += (float)v[q];
      }
      const float inv = 1.f / ssum[rr][hh];
      f16x8 xv;
#pragma unroll
      for (int q = 0; q < 8; ++q) xv[q] = (_Float16)(sm8[q] * inv);
      *(f16x8*)&xs[rr][c8] = xv;
    }
  }
  __syncthreads();
  // MFMA GEMM: y = xs @ fuse_W^T
  const int cbase = w * 64 + col;
  f32x4 acc0 = {0.f, 0.f, 0.f, 0.f}, acc1 = acc0, acc2 = acc0, acc3 = acc0;
  const float* wr0 = fW + (size_t)cbase * F + kg * 8;
  const float* wr1 = wr0 + (size_t)16 * F;
  const float* wr2 = wr0 + (size_t)32 * F;
  const float* wr3 = wr0 + (size_t)48 * F;
  for (int ks = 0; ks < 8; ++ks) {
    const int k0 = ks * 32;
    const f16x8 af = *(const f16x8*)&xs[col][k0 + kg * 8];
    f16x8 bf0, bf1, bf2, bf3;
#define LDB(dst, ptr)                                                     \
    {                                                                     \
      const f32x4 a = *(const f32x4*)((ptr) + k0);                        \
      const f32x4 b = *(const f32x4*)((ptr) + k0 + 4);                    \
      _Pragma("unroll")                                                   \
      for (int e = 0; e < 4; ++e) { dst[e] = (_Float16)a[e]; dst[4 + e] = (_Float16)b[e]; } \
    }
    LDB(bf0, wr0) LDB(bf1, wr1) LDB(bf2, wr2) LDB(bf3, wr3)
#undef LDB
    acc0 = __builtin_amdgcn_mfma_f32_16x16x32_f16(af, bf0, acc0, 0, 0, 0);
    acc1 = __builtin_amdgcn_mfma_f32_16x16x32_f16(af, bf1, acc1, 0, 0, 0);
    acc2 = __builtin_amdgcn_mfma_f32_16x16x32_f16(af, bf2, acc2, 0, 0, 0);
    acc3 = __builtin_amdgcn_mfma_f32_16x16x32_f16(af, bf3, acc3, 0, 0, 0);
  }
  // + bias (pre-LN)
  const float fb0 = fb[cbase], fb1 = fb[cbase + 16], fb2 = fb[cbase + 32], fb3 = fb[cbase + 48];
#pragma unroll
  for (int r = 0; r < 4; ++r) {
    acc0[r] += fb0; acc1[r] += fb1; acc2[r] += fb2; acc3[r] += fb3;
  }
  // LN stats: per-lane 4-col partials -> 16-lane shfl -> 4-wave LDS reduce
  float sm[4], sq[4];
#pragma unroll
  for (int r = 0; r < 4; ++r) {
    sm[r] = acc0[r] + acc1[r] + acc2[r] + acc3[r];
    sq[r] = acc0[r] * acc0[r] + acc1[r] * acc1[r] + acc2[r] * acc2[r] + acc3[r] * acc3[r];
#pragma unroll
    for (int off = 1; off < 16; off <<= 1) {
      sm[r] += __shfl_xor(sm[r], off);
      sq[r] += __shfl_xor(sq[r], off);
    }
  }
  if (col == 0) {
#pragma unroll
    for (int r = 0; r < 4; ++r) {
      red[0][w][kg * 4 + r] = sm[r];
      red[1][w][kg * 4 + r] = sq[r];
    }
  }
  __syncthreads();
  const float g0 = ln_g[cbase], g1 = ln_g[cbase + 16], g2 = ln_g[cbase + 32], g3 = ln_g[cbase + 48];
  const float b0 = ln_b[cbase], b1 = ln_b[cbase + 16], b2 = ln_b[cbase + 32], b3 = ln_b[cbase + 48];
#pragma unroll
  for (int r = 0; r < 4; ++r) {
    const int row = kg * 4 + r;
    const float S = red[0][0][row] + red[0][1][row] + red[0][2][row] + red[0][3][row];
    const float Q = red[1][0][row] + red[1][1][row] + red[1][2][row] + red[1][3][row];
    const float mu = S * (1.f / F);
    const float rs = rsqrtf(Q * (1.f / F) - mu * mu + LN_EPS);
    float* orow = out + (size_t)(i0 + row) * F;
    orow[cbase] = fmaxf((acc0[r] - mu) * rs * g0 + b0, 0.f);
    orow[cbase + 16] = fmaxf((acc1[r] - mu) * rs * g1 + b1, 0.f);
    orow[cbase + 32] = fmaxf((acc2[r] - mu) * rs * g2 + b2, 0.f);
    orow[cbase + 48] = fmaxf((acc3[r] - mu) * rs * g3 + b3, 0.f);
  }
}

extern "C" void kernel_launch(void* const* d_in, const int* in_sizes, int n_in,
                              void* d_out, int out_size, void* d_ws, size_t ws_size,
                              hipStream_t stream) {
  const float* x = (const float*)d_in[0];
  const float* adj = (const float*)d_in[1];
  const float* W = (const float*)d_in[2];
  const float* attn_src = (const float*)d_in[3];
  const float* attn_dst = (const float*)d_in[4];
  const float* edge_W = (const float*)d_in[5];
  const float* edge_b = (const float*)d_in[6];
  const float* fuse_W = (const float*)d_in[7];
  const float* fuse_b = (const float*)d_in[8];
  const float* ln_g = (const float*)d_in[9];
  const float* ln_b = (const float*)d_in[10];
  float* out = (float*)d_out;

  // workspace layout (KC chosen to fit ws_size)
  const size_t fixedB = (size_t)NN * F * 2 + 2 * (size_t)NN * NH * 4;
  const size_t perKC = (size_t)NN * NH * 4 + (size_t)NN * F * 2;  // swp + part
  const int kcn = (fixedB + 8 * perKC <= ws_size) ? 8 : 4;

  char* p = (char*)d_ws;
  _Float16* hblk = (_Float16*)p;  p += (size_t)NN * F * 2;
  float* a_src = (float*)p;       p += (size_t)NN * NH * 4;
  float* a_dstT = (float*)p;      p += (size_t)NN * NH * 4;
  float* swp = (float*)p;         p += (size_t)kcn * NN * NH * 4;
  _Float16* part = (_Float16*)p;

  gemm_h_mfma<<<192, 256, 0, stream>>>(x, W, attn_src, attn_dst, hblk, a_src, a_dstT);
  if (kcn == 8) {
    gat_mfma<8><<<192 * 8, 256, 0, stream>>>(adj, hblk, a_src, a_dstT, edge_W, edge_b, part, swp);
    fuse_ln_mfma<8><<<192, 256, 0, stream>>>(part, swp, fuse_W, fuse_b, ln_g, ln_b, out);
  } else {
    gat_mfma<4><<<192 * 4, 256, 0, stream>>>(adj, hblk, a_src, a_dstT, edge_W, edge_b, part, swp);
    fuse_ln_mfma<4><<<192, 256, 0, stream>>>(part, swp, fuse_W, fuse_b, ln_g, ln_b, out);
  }
}